// Round 10
// baseline (1132.029 us; speedup 1.0000x reference)
//
#include <hip/hip_runtime.h>
#include <hip/hip_bf16.h>
#include <hip/hip_cooperative_groups.h>
#include <cmath>

namespace cg = cooperative_groups;

// ---------------------------------------------------------------------------
// StackAttCore: 3x LSTM + 2x additive attention. B=256 L=196 R=1024 A=512 E=1024
// Round 10: persistent cooperative megakernel (12 grid syncs replace 15
// kernel-launch boundaries). Phase bodies = R8-proven. Fallback = R8 path.
// ---------------------------------------------------------------------------

#define B_ 256
#define L_ 196
#define R_ 1024
#define A_ 512

typedef __attribute__((ext_vector_type(8))) short bf16x8;
typedef __attribute__((ext_vector_type(4))) float f32x4;

__device__ inline ushort f2bf(float f) {
  __hip_bfloat16 h = __float2bfloat16(f);
  return *(ushort*)&h;
}
__device__ inline uint pk2bf(float lo, float hi) {
  float2 t; t.x = lo; t.y = hi;
  __hip_bfloat162 h = __float22bfloat162_rn(t);
  return *(uint*)&h;
}
__device__ inline float ftanh(float x) {
  float e = __expf(2.f * x);
  return 1.f - 2.f / (e + 1.f);
}

struct MP {
  const float *xt, *fc, *feats, *p_att, *st_h, *st_c;
  const float *wi0, *bi0, *wh0, *bh0;
  const float *wi1, *bi1, *wh1, *bh1;
  const float *wi2, *bi2, *wh2, *bh2;
  const float *hw1, *hb1, *aw1, *ab1;
  const float *hw2, *hb2, *aw2, *ab2;
  const float *emb2w, *emb2b;
  float *out_h2, *out_h, *out_c;
  float *Sp, *attHp, *sc;      // q2p aliases attHp (disjoint in time)
  ushort *Xb0, *Xb1, *Xb2, *q2b;
};

// ---------------------------------------------------------------------------
// Megakernel. Phases separated by grid.sync():
//  pack | gemmL0 | gates0 | attH1 | scores1 | smw1 | gemmL1+q2 | gates1(+q2b)
//  | attH2 | scores2 | smw2 | gemmL2 | gates2
// ---------------------------------------------------------------------------
__global__ void __launch_bounds__(256, 4) mega(MP p)
{
  cg::grid_group grid = cg::this_grid();
  __shared__ __align__(16) char smemraw[32768];
  ushort (*lA)[4096] = (ushort (*)[4096])smemraw;            // gemm: 2 x 8KB
  ushort (*lB)[4096] = (ushort (*)[4096])(smemraw + 16384);  // gemm: 2 x 8KB
  float* red  = (float*)smemraw;            // smw: 256 f
  float* wbuf = (float*)(smemraw + 1024);   // smw: 208 f
  f32x4* partb = (f32x4*)(smemraw + 2048);  // smw: 3*64 f32x4

  const int tid = threadIdx.x;
  const int lane = tid & 63;
  const int wv = tid >> 6;

  // ---- gemm per-thread constants (tile 64x64, BK=64, 4 waves 2x2)
  const int srow = tid >> 2;
  const int sq = tid & 3;
  const int wz0 = srow * 64 + (((sq * 2) ^ (srow & 7)) * 8);
  const int wz1 = srow * 64 + (((sq * 2 + 1) ^ (srow & 7)) * 8);
  const int wr = wv >> 1, wc = wv & 1;
  const int l15 = lane & 15, l4 = lane >> 4;
  int aoff[2][2], boff[2][2];
#pragma unroll
  for (int m = 0; m < 2; m++)
#pragma unroll
    for (int s = 0; s < 2; s++) {
      int ra = wr * 32 + m * 16 + l15;
      int rb = wc * 32 + m * 16 + l15;
      int sl = s * 4 + l4;
      aoff[m][s] = ra * 64 + ((sl ^ (ra & 7)) * 8);
      boff[m][s] = rb * 64 + ((sl ^ (rb & 7)) * 8);
    }

  // ---- gemm phase: C[z][256,N] += Xb[:,k0:k0+Ks] @ [W1|W2]^T  (vb loop)
  auto gemm = [&](const ushort* Xb, int ldx,
                  const float* W1, int ldw1, int K1,
                  const float* W2, int ldw2,
                  int K, int nbn, int ns, float* C, int ldc) {
    const int Ks = K / ns;
    const int NT = Ks >> 6;
    const size_t pstride = (size_t)256 * ldc;
    const int total = nbn * 4 * ns;
    for (int vb = blockIdx.x; vb < total; vb += gridDim.x) {
      const int n0 = (vb % nbn) * 64;
      const int r = vb / nbn;
      const int m0 = (r & 3) * 64;
      const int z = r >> 2;
      const int k0 = z * Ks;
      float* Cz = C + (size_t)z * pstride;

      f32x4 zero = {0.f, 0.f, 0.f, 0.f};
      f32x4 a00 = zero, a01 = zero, a10 = zero, a11 = zero;
      uint4 ax0, ax1;
      f32x4 bw0, bw1, bw2, bw3;
      const ushort* aB = Xb + (size_t)(m0 + srow) * ldx + sq * 16;

      auto g_load = [&](int kt) {
        const int kk = k0 + kt * 64;
        ax0 = *(const uint4*)(aB + kk);
        ax1 = *(const uint4*)(aB + kk + 8);
        const float* wp = (kk < K1)
            ? W1 + (size_t)(n0 + srow) * ldw1 + kk + sq * 16
            : W2 + (size_t)(n0 + srow) * ldw2 + (kk - K1) + sq * 16;
        bw0 = *(const f32x4*)wp;
        bw1 = *(const f32x4*)(wp + 4);
        bw2 = *(const f32x4*)(wp + 8);
        bw3 = *(const f32x4*)(wp + 12);
      };
      auto s_write = [&](int buf) {
        *(uint4*)&lA[buf][wz0] = ax0;
        *(uint4*)&lA[buf][wz1] = ax1;
        uint4 b0, b1;
        b0.x = pk2bf(bw0.x, bw0.y); b0.y = pk2bf(bw0.z, bw0.w);
        b0.z = pk2bf(bw1.x, bw1.y); b0.w = pk2bf(bw1.z, bw1.w);
        b1.x = pk2bf(bw2.x, bw2.y); b1.y = pk2bf(bw2.z, bw2.w);
        b1.z = pk2bf(bw3.x, bw3.y); b1.w = pk2bf(bw3.z, bw3.w);
        *(uint4*)&lB[buf][wz0] = b0;
        *(uint4*)&lB[buf][wz1] = b1;
      };
      auto compute = [&](int buf) {
#pragma unroll
        for (int s = 0; s < 2; s++) {
          bf16x8 af0 = *(const bf16x8*)&lA[buf][aoff[0][s]];
          bf16x8 af1 = *(const bf16x8*)&lA[buf][aoff[1][s]];
          bf16x8 bf0 = *(const bf16x8*)&lB[buf][boff[0][s]];
          bf16x8 bf1 = *(const bf16x8*)&lB[buf][boff[1][s]];
          a00 = __builtin_amdgcn_mfma_f32_16x16x32_bf16(af0, bf0, a00, 0, 0, 0);
          a01 = __builtin_amdgcn_mfma_f32_16x16x32_bf16(af0, bf1, a01, 0, 0, 0);
          a10 = __builtin_amdgcn_mfma_f32_16x16x32_bf16(af1, bf0, a10, 0, 0, 0);
          a11 = __builtin_amdgcn_mfma_f32_16x16x32_bf16(af1, bf1, a11, 0, 0, 0);
        }
      };

      g_load(0);
      s_write(0);
      __syncthreads();
      int cur = 0;
      for (int kt = 0; kt < NT; kt++) {
        if (kt + 1 < NT) g_load(kt + 1);
        compute(cur);
        if (kt + 1 < NT) s_write(cur ^ 1);
        __syncthreads();
        cur ^= 1;
      }

      // epilogue
      {
        const int colb = n0 + wc * 32 + l15;
        const int rowb = m0 + wr * 32 + l4 * 4;
#pragma unroll
        for (int j2 = 0; j2 < 4; j2++) {
          Cz[(size_t)(rowb + j2) * ldc + colb]           = a00[j2];
          Cz[(size_t)(rowb + j2) * ldc + colb + 16]      = a01[j2];
          Cz[(size_t)(rowb + 16 + j2) * ldc + colb]      = a10[j2];
          Cz[(size_t)(rowb + 16 + j2) * ldc + colb + 16] = a11[j2];
        }
      }
    }
  };

  // ---- gates phase (Sp has 3 partial slices); optional q2b fusion (4 slices)
  auto gates = [&](const float* bi, const float* bh, const float* c_prev,
                   float* h_out, float* c_out, ushort* hb16, float* h_out2,
                   const float* q2pp, const float* eb) {
    for (int i = blockIdx.x * 256 + tid; i < 65536; i += gridDim.x * 256) {
      const int b = i >> 8;
      const int c4 = (i & 255) * 4;
      const size_t base = (size_t)b * 5120 + c4;
      f32x4 g0 = {0.f,0.f,0.f,0.f}, g1 = g0, g2 = g0, g3 = g0, g4 = g0;
      for (int s = 0; s < 3; s++) {
        const float* sp = p.Sp + (size_t)s * 1310720 + base;
        g0 += *(const f32x4*)(sp);
        g1 += *(const f32x4*)(sp + 1024);
        g2 += *(const f32x4*)(sp + 2048);
        g3 += *(const f32x4*)(sp + 3072);
        g4 += *(const f32x4*)(sp + 4096);
      }
      g0 += *(const f32x4*)(bi + c4)        + *(const f32x4*)(bh + c4);
      g1 += *(const f32x4*)(bi + 1024 + c4) + *(const f32x4*)(bh + 1024 + c4);
      g2 += *(const f32x4*)(bi + 2048 + c4) + *(const f32x4*)(bh + 2048 + c4);
      g3 += *(const f32x4*)(bi + 3072 + c4) + *(const f32x4*)(bh + 3072 + c4);
      g4 += *(const f32x4*)(bi + 4096 + c4) + *(const f32x4*)(bh + 4096 + c4);

      const int oidx = b * 1024 + c4;
      f32x4 cp = *(const f32x4*)(c_prev + oidx);
      f32x4 hv, cv;
#pragma unroll
      for (int k = 0; k < 4; k++) {
        float ig = 1.f / (1.f + __expf(-g0[k]));
        float fg = 1.f / (1.f + __expf(-g1[k]));
        float og = 1.f / (1.f + __expf(-g2[k]));
        float it = fmaxf(g3[k], g4[k]);
        float c = fg * cp[k] + ig * it;
        cv[k] = c;
        hv[k] = og * ftanh(c);
      }
      *(f32x4*)(h_out + oidx) = hv;
      *(f32x4*)(c_out + oidx) = cv;
      if (hb16) {
        uint2 o;
        o.x = pk2bf(hv[0], hv[1]);
        o.y = pk2bf(hv[2], hv[3]);
        *(uint2*)(hb16 + (size_t)b * 3072 + c4) = o;
      }
      if (h_out2) *(f32x4*)(h_out2 + oidx) = hv;
      if (q2pp) {
        f32x4 a = hv;
        for (int s = 0; s < 4; s++)
          a += *(const f32x4*)(q2pp + (size_t)s * 262144 + oidx);
        a += *(const f32x4*)(eb + c4);
        uint2 o;
        o.x = pk2bf(a[0], a[1]);
        o.y = pk2bf(a[2], a[3]);
        *(uint2*)(p.q2b + oidx) = o;
      }
    }
  };

  // ---- scores phase: 12544 vb (4 waves each -> 50176 (b,l) pairs)
  auto scores = [&](const float* attHp, int nsA, const float* hb,
                    const float* aw, const float* ab) {
    f32x4 w0 = *(const f32x4*)(aw + lane * 8);
    f32x4 w1 = *(const f32x4*)(aw + lane * 8 + 4);
    f32x4 h0 = *(const f32x4*)(hb + lane * 8);
    f32x4 h1 = *(const f32x4*)(hb + lane * 8 + 4);
    const float abv = ab[0];
    for (int vb = blockIdx.x; vb < 12544; vb += gridDim.x) {
      const int wid = vb * 4 + wv;
      const int b = wid / L_;
      const int l = wid - b * L_;
      f32x4 q0 = {0.f,0.f,0.f,0.f}, q1 = q0;
      for (int s = 0; s < nsA; s++) {
        const float* qp = attHp + (size_t)s * 131072 + (size_t)b * A_ + lane * 8;
        q0 += *(const f32x4*)qp;
        q1 += *(const f32x4*)(qp + 4);
      }
      q0 += h0;
      q1 += h1;
      const float* pp = p.p_att + ((size_t)b * L_ + l) * A_ + lane * 8;
      f32x4 p0 = *(const f32x4*)pp;
      f32x4 p1 = *(const f32x4*)(pp + 4);
      float prt = 0.f;
#pragma unroll
      for (int k = 0; k < 4; k++) prt += ftanh(p0[k] + q0[k]) * w0[k];
#pragma unroll
      for (int k = 0; k < 4; k++) prt += ftanh(p1[k] + q1[k]) * w1[k];
#pragma unroll
      for (int off = 32; off > 0; off >>= 1) prt += __shfl_down(prt, off);
      if (lane == 0) p.sc[wid] = prt + abv;
    }
  };

  // ---- smw phase: softmax(196) + weighted feats sum -> bf16 (1024 vb)
  auto smw = [&](ushort* dst) {
    const int q = tid & 63;
    const int ph = tid >> 6;
    for (int vb = blockIdx.x; vb < 1024; vb += gridDim.x) {
      const int b = vb >> 2;
      const int dc = vb & 3;
      float v = (tid < L_) ? p.sc[b * L_ + tid] : -1e30f;
      red[tid] = v;
      __syncthreads();
      for (int s = 128; s > 0; s >>= 1) {
        if (tid < s) red[tid] = fmaxf(red[tid], red[tid + s]);
        __syncthreads();
      }
      float m = red[0];
      __syncthreads();
      float e = (tid < L_) ? __expf(v - m) : 0.f;
      red[tid] = e;
      __syncthreads();
      for (int s = 128; s > 0; s >>= 1) {
        if (tid < s) red[tid] += red[tid + s];
        __syncthreads();
      }
      if (tid < L_) wbuf[tid] = e * (1.f / red[0]);
      __syncthreads();

      const int col = dc * 256 + q * 4;
      const float* f = p.feats + (size_t)b * L_ * R_ + col;
      f32x4 acc = {0.f, 0.f, 0.f, 0.f};
#pragma unroll 7
      for (int l = ph; l < L_; l += 4)
        acc += wbuf[l] * *(const f32x4*)(f + (size_t)l * R_);
      if (ph != 0) partb[(ph - 1) * 64 + q] = acc;
      __syncthreads();
      if (ph == 0) {
        acc += partb[q];
        acc += partb[64 + q];
        acc += partb[128 + q];
        uint2 o;
        o.x = pk2bf(acc[0], acc[1]);
        o.y = pk2bf(acc[2], acc[3]);
        *(uint2*)(dst + (size_t)b * 3072 + col) = o;
      }
      __syncthreads();
    }
  };

  // ---- pack phase: 5 fp32 [256,1024] segments -> bf16 (stride 3072)
  auto pack = [&]() {
    for (int vb = blockIdx.x; vb < 1280; vb += gridDim.x) {
      const int seg = vb >> 8;
      const int row = vb & 255;
      const int col = tid * 4;
      const float* s;
      ushort* d;
      switch (seg) {
        case 0: s = p.xt; d = p.Xb0; break;
        case 1: s = p.fc; d = p.Xb0 + 1024; break;
        case 2: s = p.st_h; d = p.Xb0 + 2048; break;
        case 3: s = p.st_h + 262144; d = p.Xb1 + 2048; break;
        default: s = p.st_h + 524288; d = p.Xb2 + 2048; break;
      }
      float4 v = *(const float4*)(s + (size_t)row * 1024 + col);
      uint2 o;
      o.x = pk2bf(v.x, v.y);
      o.y = pk2bf(v.z, v.w);
      *(uint2*)(d + (size_t)row * 3072 + col) = o;
    }
  };

  // ======================= pipeline =======================
  pack();                                                            grid.sync();
  gemm(p.Xb0, 3072, p.wi0, 2048, 2048, p.wh0, 1024, 3072, 80, 3, p.Sp, 5120);
                                                                     grid.sync();
  gates(p.bi0, p.bh0, p.st_c, p.out_h, p.out_c, p.Xb1, nullptr, nullptr, nullptr);
                                                                     grid.sync();
  gemm(p.Xb1, 3072, p.hw1, 1024, 1024, p.hw1, 1024, 1024, 8, 8, p.attHp, 512);
                                                                     grid.sync();
  scores(p.attHp, 8, p.hb1, p.aw1, p.ab1);                           grid.sync();
  smw(p.Xb1 + 1024);                                                 grid.sync();
  gemm(p.Xb1, 3072, p.wi1, 2048, 2048, p.wh1, 1024, 3072, 80, 3, p.Sp, 5120);
  gemm(p.Xb1 + 1024, 3072, p.emb2w, 1024, 1024, p.emb2w, 1024, 1024, 16, 4,
       p.attHp /*q2p alias*/, 1024);                                 grid.sync();
  gates(p.bi1, p.bh1, p.st_c + 262144, p.out_h + 262144, p.out_c + 262144,
        p.Xb2, nullptr, p.attHp /*q2p*/, p.emb2b);                   grid.sync();
  gemm((const ushort*)p.q2b, 1024, p.hw2, 1024, 1024, p.hw2, 1024, 1024, 8, 8,
       p.attHp, 512);                                                grid.sync();
  scores(p.attHp, 8, p.hb2, p.aw2, p.ab2);                           grid.sync();
  smw(p.Xb2 + 1024);                                                 grid.sync();
  gemm(p.Xb2, 3072, p.wi2, 2048, 2048, p.wh2, 1024, 3072, 80, 3, p.Sp, 5120);
                                                                     grid.sync();
  gates(p.bi2, p.bh2, p.st_c + 524288, p.out_h + 524288, p.out_c + 524288,
        nullptr, p.out_h2, nullptr, nullptr);
}

// ===========================================================================
// Fallback path: R8 multi-kernel version (proven 304.8 us)
// ===========================================================================
__global__ __launch_bounds__(256) void fb_gemm(
    float* __restrict__ C, int ldc, size_t pstride,
    const ushort* __restrict__ Xb, int ldx,
    const float* __restrict__ W1, int ldw1, int K1,
    const float* __restrict__ W2, int ldw2,
    int K, int nbn, int ns)
{
  __shared__ ushort lA[2][64 * 64];
  __shared__ ushort lB[2][64 * 64];
  const int tid = threadIdx.x;
  const int flat = blockIdx.x;
  const int n0 = (flat % nbn) * 64;
  const int r = flat / nbn;
  const int m0 = (r & 3) * 64;
  const int z = r >> 2;
  const int Ks = K / ns;
  const int k0 = z * Ks;
  C += (size_t)z * pstride;

  const int srow = tid >> 2;
  const int sq = tid & 3;
  const int wz0 = srow * 64 + (((sq * 2) ^ (srow & 7)) * 8);
  const int wz1 = srow * 64 + (((sq * 2 + 1) ^ (srow & 7)) * 8);
  const int lane = tid & 63;
  const int wid = tid >> 6;
  const int wr = wid >> 1, wc = wid & 1;
  const int l15 = lane & 15, l4 = lane >> 4;
  int aoff[2][2], boff[2][2];
#pragma unroll
  for (int m = 0; m < 2; m++)
#pragma unroll
    for (int s = 0; s < 2; s++) {
      int ra = wr * 32 + m * 16 + l15;
      int rb = wc * 32 + m * 16 + l15;
      int sl = s * 4 + l4;
      aoff[m][s] = ra * 64 + ((sl ^ (ra & 7)) * 8);
      boff[m][s] = rb * 64 + ((sl ^ (rb & 7)) * 8);
    }

  f32x4 zero = {0.f, 0.f, 0.f, 0.f};
  f32x4 acc[2][2];
  acc[0][0] = zero; acc[0][1] = zero; acc[1][0] = zero; acc[1][1] = zero;
  uint4 ax0, ax1;
  f32x4 bw[4];
  const int NT = Ks >> 6;

  auto g_load = [&](int kt) {
    const int kk = k0 + kt * 64;
    const ushort* ap = Xb + (size_t)(m0 + srow) * ldx + kk + sq * 16;
    ax0 = *(const uint4*)ap;
    ax1 = *(const uint4*)(ap + 8);
    const float* wp;
    if (kk < K1) wp = W1 + (size_t)(n0 + srow) * ldw1 + kk + sq * 16;
    else         wp = W2 + (size_t)(n0 + srow) * ldw2 + (kk - K1) + sq * 16;
    bw[0] = *(const f32x4*)wp;
    bw[1] = *(const f32x4*)(wp + 4);
    bw[2] = *(const f32x4*)(wp + 8);
    bw[3] = *(const f32x4*)(wp + 12);
  };
  auto s_write = [&](int buf) {
    *(uint4*)&lA[buf][wz0] = ax0;
    *(uint4*)&lA[buf][wz1] = ax1;
    uint4 b0, b1;
    b0.x = pk2bf(bw[0].x, bw[0].y); b0.y = pk2bf(bw[0].z, bw[0].w);
    b0.z = pk2bf(bw[1].x, bw[1].y); b0.w = pk2bf(bw[1].z, bw[1].w);
    b1.x = pk2bf(bw[2].x, bw[2].y); b1.y = pk2bf(bw[2].z, bw[2].w);
    b1.z = pk2bf(bw[3].x, bw[3].y); b1.w = pk2bf(bw[3].z, bw[3].w);
    *(uint4*)&lB[buf][wz0] = b0;
    *(uint4*)&lB[buf][wz1] = b1;
  };
  auto compute = [&](int buf) {
#pragma unroll
    for (int s = 0; s < 2; s++) {
      bf16x8 af0 = *(const bf16x8*)&lA[buf][aoff[0][s]];
      bf16x8 af1 = *(const bf16x8*)&lA[buf][aoff[1][s]];
      bf16x8 bf0 = *(const bf16x8*)&lB[buf][boff[0][s]];
      bf16x8 bf1 = *(const bf16x8*)&lB[buf][boff[1][s]];
      acc[0][0] = __builtin_amdgcn_mfma_f32_16x16x32_bf16(af0, bf0, acc[0][0], 0, 0, 0);
      acc[0][1] = __builtin_amdgcn_mfma_f32_16x16x32_bf16(af0, bf1, acc[0][1], 0, 0, 0);
      acc[1][0] = __builtin_amdgcn_mfma_f32_16x16x32_bf16(af1, bf0, acc[1][0], 0, 0, 0);
      acc[1][1] = __builtin_amdgcn_mfma_f32_16x16x32_bf16(af1, bf1, acc[1][1], 0, 0, 0);
    }
  };

  g_load(0);
  s_write(0);
  __syncthreads();
  int cur = 0;
  for (int kt = 0; kt < NT; kt++) {
    if (kt + 1 < NT) g_load(kt + 1);
    compute(cur);
    if (kt + 1 < NT) s_write(cur ^ 1);
    __syncthreads();
    cur ^= 1;
  }

#pragma unroll
  for (int m = 0; m < 2; m++)
#pragma unroll
    for (int n = 0; n < 2; n++) {
      const int col = n0 + wc * 32 + n * 16 + l15;
#pragma unroll
      for (int j2 = 0; j2 < 4; j2++) {
        const int row = m0 + wr * 32 + m * 16 + l4 * 4 + j2;
        C[(size_t)row * ldc + col] = acc[m][n][j2];
      }
    }
}

__global__ __launch_bounds__(256) void fb_pack5(
    const float* __restrict__ s0, ushort* __restrict__ d0,
    const float* __restrict__ s1, ushort* __restrict__ d1,
    const float* __restrict__ s2, ushort* __restrict__ d2,
    const float* __restrict__ s3, ushort* __restrict__ d3,
    const float* __restrict__ s4, ushort* __restrict__ d4)
{
  const int seg = blockIdx.x >> 8;
  const int row = blockIdx.x & 255;
  const int col = threadIdx.x * 4;
  const float* s;
  ushort* d;
  switch (seg) {
    case 0: s = s0; d = d0; break;
    case 1: s = s1; d = d1; break;
    case 2: s = s2; d = d2; break;
    case 3: s = s3; d = d3; break;
    default: s = s4; d = d4; break;
  }
  float4 v = *(const float4*)(s + (size_t)row * 1024 + col);
  uint2 o;
  o.x = pk2bf(v.x, v.y);
  o.y = pk2bf(v.z, v.w);
  *(uint2*)(d + (size_t)row * 3072 + col) = o;
}

__global__ __launch_bounds__(256) void fb_gates(
    const float* __restrict__ Sp, int ns,
    const float* __restrict__ bi, const float* __restrict__ bh,
    const float* __restrict__ c_prev,
    float* __restrict__ h_out, float* __restrict__ c_out,
    ushort* __restrict__ hb16,
    float* __restrict__ h_out2)
{
  const int idx = blockIdx.x * 256 + threadIdx.x;
  const int b = idx >> 8;
  const int c4 = (idx & 255) * 4;
  const size_t base = (size_t)b * 5120 + c4;
  f32x4 g[5];
#pragma unroll
  for (int j = 0; j < 5; j++) g[j] = (f32x4){0.f, 0.f, 0.f, 0.f};
  for (int s = 0; s < ns; s++) {
    const float* sp = Sp + (size_t)s * 1310720 + base;
#pragma unroll
    for (int j = 0; j < 5; j++) g[j] += *(const f32x4*)(sp + j * 1024);
  }
#pragma unroll
  for (int j = 0; j < 5; j++) {
    g[j] += *(const f32x4*)(bi + j * 1024 + c4);
    g[j] += *(const f32x4*)(bh + j * 1024 + c4);
  }
  const int oidx = b * 1024 + c4;
  f32x4 cp = *(const f32x4*)(c_prev + oidx);
  f32x4 hv, cv;
#pragma unroll
  for (int i = 0; i < 4; i++) {
    float ig = 1.f / (1.f + __expf(-g[0][i]));
    float fg = 1.f / (1.f + __expf(-g[1][i]));
    float og = 1.f / (1.f + __expf(-g[2][i]));
    float it = fmaxf(g[3][i], g[4][i]);
    float c = fg * cp[i] + ig * it;
    cv[i] = c;
    hv[i] = og * ftanh(c);
  }
  *(f32x4*)(h_out + oidx) = hv;
  *(f32x4*)(c_out + oidx) = cv;
  if (hb16) {
    uint2 o;
    o.x = pk2bf(hv[0], hv[1]);
    o.y = pk2bf(hv[2], hv[3]);
    *(uint2*)(hb16 + (size_t)b * 3072 + c4) = o;
  }
  if (h_out2) *(f32x4*)(h_out2 + oidx) = hv;
}

__global__ __launch_bounds__(256) void fb_scores(
    float* __restrict__ scores,
    const float* __restrict__ p_att,
    const float* __restrict__ attHp, int ns,
    const float* __restrict__ hb,
    const float* __restrict__ aw,
    const float* __restrict__ ab)
{
  int wid = blockIdx.x * 4 + (threadIdx.x >> 6);
  if (wid >= B_ * L_) return;
  int lane = threadIdx.x & 63;
  int b = wid / L_;
  int l = wid % L_;
  const float* p = p_att + ((size_t)b * L_ + l) * A_;
  f32x4 q0 = {0.f, 0.f, 0.f, 0.f}, q1 = q0;
  for (int s = 0; s < ns; s++) {
    const float* qp = attHp + (size_t)s * 131072 + (size_t)b * A_ + lane * 8;
    q0 += *(const f32x4*)qp;
    q1 += *(const f32x4*)(qp + 4);
  }
  f32x4 p0 = *(const f32x4*)(p + lane * 8);
  f32x4 p1 = *(const f32x4*)(p + lane * 8 + 4);
  f32x4 h0 = *(const f32x4*)(hb + lane * 8);
  f32x4 h1 = *(const f32x4*)(hb + lane * 8 + 4);
  f32x4 w0 = *(const f32x4*)(aw + lane * 8);
  f32x4 w1 = *(const f32x4*)(aw + lane * 8 + 4);
  float part = 0.f;
#pragma unroll
  for (int i = 0; i < 4; i++) part += ftanh(p0[i] + q0[i] + h0[i]) * w0[i];
#pragma unroll
  for (int i = 0; i < 4; i++) part += ftanh(p1[i] + q1[i] + h1[i]) * w1[i];
#pragma unroll
  for (int off = 32; off > 0; off >>= 1) part += __shfl_down(part, off);
  if (lane == 0) scores[wid] = part + ab[0];
}

__global__ __launch_bounds__(256) void fb_smw(
    ushort* __restrict__ dst,
    const float* __restrict__ sc,
    const float* __restrict__ feats)
{
  const int b = blockIdx.x >> 2;
  const int dc = blockIdx.x & 3;
  const int t = threadIdx.x;
  const int q = t & 63;
  const int ph = t >> 6;
  __shared__ float red[256];
  __shared__ float wbuf[208];
  __shared__ f32x4 part[3][64];
  float v = (t < L_) ? sc[b * L_ + t] : -1e30f;
  red[t] = v;
  __syncthreads();
  for (int s = 128; s > 0; s >>= 1) {
    if (t < s) red[t] = fmaxf(red[t], red[t + s]);
    __syncthreads();
  }
  float m = red[0];
  __syncthreads();
  float e = (t < L_) ? __expf(v - m) : 0.f;
  red[t] = e;
  __syncthreads();
  for (int s = 128; s > 0; s >>= 1) {
    if (t < s) red[t] += red[t + s];
    __syncthreads();
  }
  if (t < L_) wbuf[t] = e * (1.f / red[0]);
  __syncthreads();
  const int col = dc * 256 + q * 4;
  const float* f = feats + (size_t)b * L_ * R_ + col;
  f32x4 acc = {0.f, 0.f, 0.f, 0.f};
#pragma unroll 7
  for (int l = ph; l < L_; l += 4) {
    acc += wbuf[l] * *(const f32x4*)(f + (size_t)l * R_);
  }
  if (ph != 0) part[ph - 1][q] = acc;
  __syncthreads();
  if (ph == 0) {
    acc += part[0][q];
    acc += part[1][q];
    acc += part[2][q];
    uint2 o;
    o.x = pk2bf(acc[0], acc[1]);
    o.y = pk2bf(acc[2], acc[3]);
    *(uint2*)(dst + (size_t)b * 3072 + col) = o;
  }
}

__global__ __launch_bounds__(256) void fb_makeq2(
    ushort* __restrict__ q2b, const float* __restrict__ q2p, int ns,
    const float* __restrict__ h1, const float* __restrict__ eb)
{
  const int idx = blockIdx.x * 256 + threadIdx.x;
  const int b = idx >> 8;
  const int c4 = (idx & 255) * 4;
  const int oidx = b * 1024 + c4;
  f32x4 a = {0.f, 0.f, 0.f, 0.f};
  for (int s = 0; s < ns; s++)
    a += *(const f32x4*)(q2p + (size_t)s * 262144 + oidx);
  a += *(const f32x4*)(h1 + oidx);
  a += *(const f32x4*)(eb + c4);
  uint2 o;
  o.x = pk2bf(a[0], a[1]);
  o.y = pk2bf(a[2], a[3]);
  *(uint2*)(q2b + oidx) = o;
}

extern "C" void kernel_launch(void* const* d_in, const int* in_sizes, int n_in,
                              void* d_out, int out_size, void* d_ws, size_t ws_size,
                              hipStream_t stream)
{
  const float* xt        = (const float*)d_in[0];
  const float* fc        = (const float*)d_in[1];
  const float* att_feats = (const float*)d_in[2];
  const float* p_att     = (const float*)d_in[3];
  const float* st_h      = (const float*)d_in[4];
  const float* st_c      = (const float*)d_in[5];
  const float* wi[3] = {(const float*)d_in[6],  (const float*)d_in[10], (const float*)d_in[14]};
  const float* bi[3] = {(const float*)d_in[7],  (const float*)d_in[11], (const float*)d_in[15]};
  const float* wh[3] = {(const float*)d_in[8],  (const float*)d_in[12], (const float*)d_in[16]};
  const float* bh[3] = {(const float*)d_in[9],  (const float*)d_in[13], (const float*)d_in[17]};
  const float* a_hw[2] = {(const float*)d_in[18], (const float*)d_in[22]};
  const float* a_hb[2] = {(const float*)d_in[19], (const float*)d_in[23]};
  const float* a_aw[2] = {(const float*)d_in[20], (const float*)d_in[24]};
  const float* a_ab[2] = {(const float*)d_in[21], (const float*)d_in[25]};
  const float* emb2_w = (const float*)d_in[26];
  const float* emb2_b = (const float*)d_in[27];

  float* out    = (float*)d_out;
  float* out_h2 = out;
  float* out_h  = out + 262144;
  float* out_c  = out + 262144 + 786432;
  const int BR = B_ * R_;

  // -------- try cooperative megakernel --------
  int nb = 0;
  hipError_t oe = hipOccupancyMaxActiveBlocksPerMultiprocessor(&nb, mega, 256, 0);
  if (oe == hipSuccess && nb >= 1) {
    // mega ws layout: Sp 3 slices | Xb0..2 | attHp(=q2p) 8 slices | sc | q2b
    float*  Sp    = (float*)d_ws;                        // 3 x 1310720 f
    ushort* Xb0   = (ushort*)(Sp + 3 * 1310720);
    ushort* Xb1   = Xb0 + 786432;
    ushort* Xb2   = Xb1 + 786432;
    float*  attHp = (float*)(Xb2 + 786432);              // 1048576 f
    float*  sc    = attHp + 1048576;                     // 50176 f
    ushort* q2b   = (ushort*)(sc + 50176);               // 262144 us

    MP p;
    p.xt = xt; p.fc = fc; p.feats = att_feats; p.p_att = p_att;
    p.st_h = st_h; p.st_c = st_c;
    p.wi0 = wi[0]; p.bi0 = bi[0]; p.wh0 = wh[0]; p.bh0 = bh[0];
    p.wi1 = wi[1]; p.bi1 = bi[1]; p.wh1 = wh[1]; p.bh1 = bh[1];
    p.wi2 = wi[2]; p.bi2 = bi[2]; p.wh2 = wh[2]; p.bh2 = bh[2];
    p.hw1 = a_hw[0]; p.hb1 = a_hb[0]; p.aw1 = a_aw[0]; p.ab1 = a_ab[0];
    p.hw2 = a_hw[1]; p.hb2 = a_hb[1]; p.aw2 = a_aw[1]; p.ab2 = a_ab[1];
    p.emb2w = emb2_w; p.emb2b = emb2_b;
    p.out_h2 = out_h2; p.out_h = out_h; p.out_c = out_c;
    p.Sp = Sp; p.attHp = attHp; p.sc = sc;
    p.Xb0 = Xb0; p.Xb1 = Xb1; p.Xb2 = Xb2; p.q2b = q2b;

    int G = nb * 256;
    if (G > 1280) G = 1280;
    void* args[] = { (void*)&p };
    hipError_t le = hipLaunchCooperativeKernel((const void*)mega, dim3(G),
                                               dim3(256), args, 0, stream);
    if (le == hipSuccess) return;
  }

  // -------- fallback: R8 multi-kernel path --------
  const int ns = 4;
  float*  Sp    = (float*)d_ws;
  ushort* Xb0   = (ushort*)(Sp + (size_t)ns * 1310720);
  ushort* Xb1   = Xb0 + 786432;
  ushort* Xb2   = Xb1 + 786432;
  float*  attHp = (float*)(Xb2 + 786432);
  float*  sc    = attHp + (size_t)ns * 131072;
  float*  q2p   = Sp;
  ushort* q2b   = (ushort*)(Sp + (size_t)ns * 262144);

  dim3 blk(256);
  auto gemmL = [&](float* C, const ushort* Xb,
                   const float* W1, int ldw1, int K1,
                   const float* W2, int ldw2) {
    dim3 grid(80 * 4 * ns);
    hipLaunchKernelGGL(fb_gemm, grid, blk, 0, stream,
                       C, 5120, (size_t)256 * 5120, Xb, 3072,
                       W1, ldw1, K1, W2, ldw2, 3072, 80, ns);
  };
  auto gemmS = [&](float* C, int ldc, const ushort* Xb, int ldx,
                   const float* W, int ldw, int K, int N) {
    dim3 grid((N / 64) * 4 * ns);
    hipLaunchKernelGGL(fb_gemm, grid, blk, 0, stream,
                       C, ldc, (size_t)256 * ldc, Xb, ldx,
                       W, ldw, K, nullptr, 0, K, N / 64, ns);
  };

  fb_pack5<<<1280, 256, 0, stream>>>(xt, Xb0, fc, Xb0 + 1024, st_h, Xb0 + 2048,
                                     st_h + BR, Xb1 + 2048,
                                     st_h + 2 * BR, Xb2 + 2048);
  gemmL(Sp, Xb0, wi[0], 2048, 2048, wh[0], 1024);
  fb_gates<<<256, 256, 0, stream>>>(Sp, ns, bi[0], bh[0], st_c,
                                    out_h, out_c, Xb1, nullptr);
  gemmS(attHp, 512, Xb1, 3072, a_hw[0], 1024, 1024, 512);
  fb_scores<<<(B_ * L_) / 4, 256, 0, stream>>>(sc, p_att, attHp, ns,
                                               a_hb[0], a_aw[0], a_ab[0]);
  fb_smw<<<B_ * 4, 256, 0, stream>>>(Xb1 + 1024, sc, att_feats);
  gemmL(Sp, Xb1, wi[1], 2048, 2048, wh[1], 1024);
  fb_gates<<<256, 256, 0, stream>>>(Sp, ns, bi[1], bh[1], st_c + BR,
                                    out_h + BR, out_c + BR, Xb2, nullptr);
  gemmS(q2p, 1024, Xb1 + 1024, 3072, emb2_w, 1024, 1024, 1024);
  fb_makeq2<<<256, 256, 0, stream>>>(q2b, q2p, ns, out_h + BR, emb2_b);
  gemmS(attHp, 512, q2b, 1024, a_hw[1], 1024, 1024, 512);
  fb_scores<<<(B_ * L_) / 4, 256, 0, stream>>>(sc, p_att, attHp, ns,
                                               a_hb[1], a_aw[1], a_ab[1]);
  fb_smw<<<B_ * 4, 256, 0, stream>>>(Xb2 + 1024, sc, att_feats);
  gemmL(Sp, Xb2, wi[2], 2048, 2048, wh[2], 1024);
  fb_gates<<<256, 256, 0, stream>>>(Sp, ns, bi[2], bh[2], st_c + 2 * BR,
                                    out_h + 2 * BR, out_c + 2 * BR,
                                    nullptr, out_h2);
}

// Round 11
// 302.080 us; speedup vs baseline: 3.7474x; 3.7474x over previous
//
#include <hip/hip_runtime.h>
#include <hip/hip_bf16.h>
#include <cmath>

// ---------------------------------------------------------------------------
// StackAttCore: 3x LSTM + 2x additive attention. B=256 L=196 R=1024 A=512 E=1024
// Round 11: R8 structure + (a) dual-job GEMM launch (LSTM1 || q2-GEMM),
// (b) make_q2 fused into gates1. 13 launches (was 15). Fallback = exact R8.
// ---------------------------------------------------------------------------

#define B_ 256
#define L_ 196
#define R_ 1024
#define A_ 512

typedef __attribute__((ext_vector_type(8))) short bf16x8;
typedef __attribute__((ext_vector_type(4))) float f32x4;

__device__ inline ushort f2bf(float f) {
  __hip_bfloat16 h = __float2bfloat16(f);
  return *(ushort*)&h;
}
__device__ inline uint pk2bf(float lo, float hi) {
  float2 t; t.x = lo; t.y = hi;
  __hip_bfloat162 h = __float22bfloat162_rn(t);
  return *(uint*)&h;
}
__device__ inline float ftanh(float x) {
  float e = __expf(2.f * x);
  return 1.f - 2.f / (e + 1.f);
}

// ---------------------------------------------------------------------------
// GEMM job descriptor. C[z][256,N] = Xb(bf16) @ [W1|W2](fp32->bf16)^T, split-K.
// ---------------------------------------------------------------------------
struct GJob {
  float* C; int ldc; size_t pstride;
  const ushort* Xb; int ldx;
  const float* W1; int ldw1; int K1;
  const float* W2; int ldw2;
  int K, nbn, ns;
};

// Tile 64x64, BK=64, 4 waves (2x2), 16x16x32 MFMA, XOR-swizzled LDS, dbuf.
// Dual-job: blocks [0,totalA) run ja, the rest run jb (flat -= totalA).
__global__ __launch_bounds__(256) void gemm_k(GJob ja, GJob jb, int totalA)
{
  const bool isA = ((int)blockIdx.x < totalA);
  GJob j = isA ? ja : jb;
  const int flat = isA ? blockIdx.x : blockIdx.x - totalA;

  __shared__ ushort lA[2][64 * 64];
  __shared__ ushort lB[2][64 * 64];
  const int tid = threadIdx.x;

  const int n0 = (flat % j.nbn) * 64;
  const int r = flat / j.nbn;
  const int m0 = (r & 3) * 64;
  const int z = r >> 2;
  const int Ks = j.K / j.ns;
  const int k0 = z * Ks;
  float* C = j.C + (size_t)z * j.pstride;

  const int srow = tid >> 2;
  const int sq = tid & 3;
  const int wz0 = srow * 64 + (((sq * 2) ^ (srow & 7)) * 8);
  const int wz1 = srow * 64 + (((sq * 2 + 1) ^ (srow & 7)) * 8);

  const int lane = tid & 63;
  const int wid = tid >> 6;
  const int wr = wid >> 1, wc = wid & 1;
  const int l15 = lane & 15, l4 = lane >> 4;
  int aoff[2][2], boff[2][2];
#pragma unroll
  for (int m = 0; m < 2; m++)
#pragma unroll
    for (int s = 0; s < 2; s++) {
      int ra = wr * 32 + m * 16 + l15;
      int rb = wc * 32 + m * 16 + l15;
      int sl = s * 4 + l4;
      aoff[m][s] = ra * 64 + ((sl ^ (ra & 7)) * 8);
      boff[m][s] = rb * 64 + ((sl ^ (rb & 7)) * 8);
    }

  f32x4 zero = {0.f, 0.f, 0.f, 0.f};
  f32x4 acc[2][2];
  acc[0][0] = zero; acc[0][1] = zero; acc[1][0] = zero; acc[1][1] = zero;

  uint4 ax0, ax1;
  f32x4 bw[4];
  const int NT = Ks >> 6;
  const ushort* aB = j.Xb + (size_t)(m0 + srow) * j.ldx + sq * 16;

  auto g_load = [&](int kt) {
    const int kk = k0 + kt * 64;
    ax0 = *(const uint4*)(aB + kk);
    ax1 = *(const uint4*)(aB + kk + 8);
    const float* wp = (kk < j.K1)
        ? j.W1 + (size_t)(n0 + srow) * j.ldw1 + kk + sq * 16
        : j.W2 + (size_t)(n0 + srow) * j.ldw2 + (kk - j.K1) + sq * 16;
    bw[0] = *(const f32x4*)wp;
    bw[1] = *(const f32x4*)(wp + 4);
    bw[2] = *(const f32x4*)(wp + 8);
    bw[3] = *(const f32x4*)(wp + 12);
  };
  auto s_write = [&](int buf) {
    *(uint4*)&lA[buf][wz0] = ax0;
    *(uint4*)&lA[buf][wz1] = ax1;
    uint4 b0, b1;
    b0.x = pk2bf(bw[0].x, bw[0].y); b0.y = pk2bf(bw[0].z, bw[0].w);
    b0.z = pk2bf(bw[1].x, bw[1].y); b0.w = pk2bf(bw[1].z, bw[1].w);
    b1.x = pk2bf(bw[2].x, bw[2].y); b1.y = pk2bf(bw[2].z, bw[2].w);
    b1.z = pk2bf(bw[3].x, bw[3].y); b1.w = pk2bf(bw[3].z, bw[3].w);
    *(uint4*)&lB[buf][wz0] = b0;
    *(uint4*)&lB[buf][wz1] = b1;
  };
  auto compute = [&](int buf) {
#pragma unroll
    for (int s = 0; s < 2; s++) {
      bf16x8 af0 = *(const bf16x8*)&lA[buf][aoff[0][s]];
      bf16x8 af1 = *(const bf16x8*)&lA[buf][aoff[1][s]];
      bf16x8 bf0 = *(const bf16x8*)&lB[buf][boff[0][s]];
      bf16x8 bf1 = *(const bf16x8*)&lB[buf][boff[1][s]];
      acc[0][0] = __builtin_amdgcn_mfma_f32_16x16x32_bf16(af0, bf0, acc[0][0], 0, 0, 0);
      acc[0][1] = __builtin_amdgcn_mfma_f32_16x16x32_bf16(af0, bf1, acc[0][1], 0, 0, 0);
      acc[1][0] = __builtin_amdgcn_mfma_f32_16x16x32_bf16(af1, bf0, acc[1][0], 0, 0, 0);
      acc[1][1] = __builtin_amdgcn_mfma_f32_16x16x32_bf16(af1, bf1, acc[1][1], 0, 0, 0);
    }
  };

  g_load(0);
  s_write(0);
  __syncthreads();
  int cur = 0;
  for (int kt = 0; kt < NT; kt++) {
    if (kt + 1 < NT) g_load(kt + 1);
    compute(cur);
    if (kt + 1 < NT) s_write(cur ^ 1);
    __syncthreads();
    cur ^= 1;
  }

#pragma unroll
  for (int m = 0; m < 2; m++)
#pragma unroll
    for (int n = 0; n < 2; n++) {
      const int col = n0 + wc * 32 + n * 16 + l15;
#pragma unroll
      for (int j2 = 0; j2 < 4; j2++) {
        const int row = m0 + wr * 32 + m * 16 + l4 * 4 + j2;
        C[(size_t)row * j.ldc + col] = acc[m][n][j2];
      }
    }
}

// pack 5 fp32 [256,1024] segments -> bf16 (dst row stride 3072)
__global__ __launch_bounds__(256) void pack5(
    const float* __restrict__ s0, ushort* __restrict__ d0,
    const float* __restrict__ s1, ushort* __restrict__ d1,
    const float* __restrict__ s2, ushort* __restrict__ d2,
    const float* __restrict__ s3, ushort* __restrict__ d3,
    const float* __restrict__ s4, ushort* __restrict__ d4)
{
  const int seg = blockIdx.x >> 8;
  const int row = blockIdx.x & 255;
  const int col = threadIdx.x * 4;
  const float* s;
  ushort* d;
  switch (seg) {
    case 0: s = s0; d = d0; break;
    case 1: s = s1; d = d1; break;
    case 2: s = s2; d = d2; break;
    case 3: s = s3; d = d3; break;
    default: s = s4; d = d4; break;
  }
  float4 v = *(const float4*)(s + (size_t)row * 1024 + col);
  uint2 o;
  o.x = pk2bf(v.x, v.y);
  o.y = pk2bf(v.z, v.w);
  *(uint2*)(d + (size_t)row * 3072 + col) = o;
}

// gates: sum ns partials, biases, activations -> h, c.
// Optional fused q2: q2b = h + sum(q2p slices) + eb  (replaces make_q2).
__global__ __launch_bounds__(256) void lstm_gates(
    const float* __restrict__ Sp, int ns,
    const float* __restrict__ bi, const float* __restrict__ bh,
    const float* __restrict__ c_prev,
    float* __restrict__ h_out, float* __restrict__ c_out,
    ushort* __restrict__ hb16,
    float* __restrict__ h_out2,
    const float* __restrict__ q2p, int q2ns,
    const float* __restrict__ eb, ushort* __restrict__ q2b)
{
  const int idx = blockIdx.x * 256 + threadIdx.x;
  const int b = idx >> 8;
  const int c4 = (idx & 255) * 4;
  const size_t base = (size_t)b * 5120 + c4;

  f32x4 g[5];
#pragma unroll
  for (int j = 0; j < 5; j++) g[j] = (f32x4){0.f, 0.f, 0.f, 0.f};
  for (int s = 0; s < ns; s++) {
    const float* sp = Sp + (size_t)s * 1310720 + base;
#pragma unroll
    for (int j = 0; j < 5; j++) g[j] += *(const f32x4*)(sp + j * 1024);
  }
#pragma unroll
  for (int j = 0; j < 5; j++) {
    g[j] += *(const f32x4*)(bi + j * 1024 + c4);
    g[j] += *(const f32x4*)(bh + j * 1024 + c4);
  }

  const int oidx = b * 1024 + c4;
  f32x4 cp = *(const f32x4*)(c_prev + oidx);
  f32x4 hv, cv;
#pragma unroll
  for (int i = 0; i < 4; i++) {
    float ig = 1.f / (1.f + __expf(-g[0][i]));
    float fg = 1.f / (1.f + __expf(-g[1][i]));
    float og = 1.f / (1.f + __expf(-g[2][i]));
    float it = fmaxf(g[3][i], g[4][i]);
    float c  = fg * cp[i] + ig * it;
    cv[i] = c;
    hv[i] = og * ftanh(c);
  }
  *(f32x4*)(h_out + oidx) = hv;
  *(f32x4*)(c_out + oidx) = cv;
  if (hb16) {
    uint2 o;
    o.x = pk2bf(hv[0], hv[1]);
    o.y = pk2bf(hv[2], hv[3]);
    *(uint2*)(hb16 + (size_t)b * 3072 + c4) = o;
  }
  if (h_out2) *(f32x4*)(h_out2 + oidx) = hv;
  if (q2p) {
    f32x4 a = hv;
    for (int s = 0; s < q2ns; s++)
      a += *(const f32x4*)(q2p + (size_t)s * 262144 + oidx);
    a += *(const f32x4*)(eb + c4);
    uint2 o;
    o.x = pk2bf(a[0], a[1]);
    o.y = pk2bf(a[2], a[3]);
    *(uint2*)(q2b + oidx) = o;
  }
}

// scores[b,l] = sum_a tanh(p + sum_s attHp[s] + hb) * aw + ab ; wave per (b,l)
__global__ __launch_bounds__(256) void att_scores(
    float* __restrict__ scores,
    const float* __restrict__ p_att,
    const float* __restrict__ attHp, int ns,
    const float* __restrict__ hb,
    const float* __restrict__ aw,
    const float* __restrict__ ab)
{
  int wid = blockIdx.x * 4 + (threadIdx.x >> 6);
  if (wid >= B_ * L_) return;
  int lane = threadIdx.x & 63;
  int b = wid / L_;
  int l = wid % L_;
  const float* p = p_att + ((size_t)b * L_ + l) * A_;

  f32x4 q0 = {0.f, 0.f, 0.f, 0.f}, q1 = q0;
  for (int s = 0; s < ns; s++) {
    const float* qp = attHp + (size_t)s * 131072 + (size_t)b * A_ + lane * 8;
    q0 += *(const f32x4*)qp;
    q1 += *(const f32x4*)(qp + 4);
  }
  f32x4 p0 = *(const f32x4*)(p + lane * 8);
  f32x4 p1 = *(const f32x4*)(p + lane * 8 + 4);
  f32x4 h0 = *(const f32x4*)(hb + lane * 8);
  f32x4 h1 = *(const f32x4*)(hb + lane * 8 + 4);
  f32x4 w0 = *(const f32x4*)(aw + lane * 8);
  f32x4 w1 = *(const f32x4*)(aw + lane * 8 + 4);
  float part = 0.f;
#pragma unroll
  for (int i = 0; i < 4; i++) part += ftanh(p0[i] + q0[i] + h0[i]) * w0[i];
#pragma unroll
  for (int i = 0; i < 4; i++) part += ftanh(p1[i] + q1[i] + h1[i]) * w1[i];
#pragma unroll
  for (int off = 32; off > 0; off >>= 1) part += __shfl_down(part, off);
  if (lane == 0) scores[wid] = part + ab[0];
}

// fused softmax(196) + weighted sum over att_feats -> bf16 (stride 3072)
__global__ __launch_bounds__(256) void att_smw(
    ushort* __restrict__ dst,
    const float* __restrict__ sc,
    const float* __restrict__ feats)
{
  const int b = blockIdx.x >> 2;
  const int dc = blockIdx.x & 3;
  const int t = threadIdx.x;
  const int q = t & 63;
  const int ph = t >> 6;
  __shared__ float red[256];
  __shared__ float wbuf[208];
  __shared__ f32x4 part[3][64];

  float v = (t < L_) ? sc[b * L_ + t] : -1e30f;
  red[t] = v;
  __syncthreads();
  for (int s = 128; s > 0; s >>= 1) {
    if (t < s) red[t] = fmaxf(red[t], red[t + s]);
    __syncthreads();
  }
  float m = red[0];
  __syncthreads();
  float e = (t < L_) ? __expf(v - m) : 0.f;
  red[t] = e;
  __syncthreads();
  for (int s = 128; s > 0; s >>= 1) {
    if (t < s) red[t] += red[t + s];
    __syncthreads();
  }
  if (t < L_) wbuf[t] = e * (1.f / red[0]);
  __syncthreads();

  const int col = dc * 256 + q * 4;
  const float* f = feats + (size_t)b * L_ * R_ + col;
  f32x4 acc = {0.f, 0.f, 0.f, 0.f};
#pragma unroll 7
  for (int l = ph; l < L_; l += 4) {
    acc += wbuf[l] * *(const f32x4*)(f + (size_t)l * R_);
  }
  if (ph != 0) part[ph - 1][q] = acc;
  __syncthreads();
  if (ph == 0) {
    acc += part[0][q];
    acc += part[1][q];
    acc += part[2][q];
    uint2 o;
    o.x = pk2bf(acc[0], acc[1]);
    o.y = pk2bf(acc[2], acc[3]);
    *(uint2*)(dst + (size_t)b * 3072 + col) = o;
  }
}

// standalone make_q2 (fallback path only)
__global__ __launch_bounds__(256) void make_q2(
    ushort* __restrict__ q2b, const float* __restrict__ q2p, int ns,
    const float* __restrict__ h1, const float* __restrict__ eb)
{
  const int idx = blockIdx.x * 256 + threadIdx.x;
  const int b = idx >> 8;
  const int c4 = (idx & 255) * 4;
  const int oidx = b * 1024 + c4;
  f32x4 a = {0.f, 0.f, 0.f, 0.f};
  for (int s = 0; s < ns; s++)
    a += *(const f32x4*)(q2p + (size_t)s * 262144 + oidx);
  a += *(const f32x4*)(h1 + oidx);
  a += *(const f32x4*)(eb + c4);
  uint2 o;
  o.x = pk2bf(a[0], a[1]);
  o.y = pk2bf(a[2], a[3]);
  *(uint2*)(q2b + oidx) = o;
}

extern "C" void kernel_launch(void* const* d_in, const int* in_sizes, int n_in,
                              void* d_out, int out_size, void* d_ws, size_t ws_size,
                              hipStream_t stream)
{
  const float* xt        = (const float*)d_in[0];
  const float* fc        = (const float*)d_in[1];
  const float* att_feats = (const float*)d_in[2];
  const float* p_att     = (const float*)d_in[3];
  const float* st_h      = (const float*)d_in[4];
  const float* st_c      = (const float*)d_in[5];
  const float* wi[3] = {(const float*)d_in[6],  (const float*)d_in[10], (const float*)d_in[14]};
  const float* bi[3] = {(const float*)d_in[7],  (const float*)d_in[11], (const float*)d_in[15]};
  const float* wh[3] = {(const float*)d_in[8],  (const float*)d_in[12], (const float*)d_in[16]};
  const float* bh[3] = {(const float*)d_in[9],  (const float*)d_in[13], (const float*)d_in[17]};
  const float* a_hw[2] = {(const float*)d_in[18], (const float*)d_in[22]};
  const float* a_hb[2] = {(const float*)d_in[19], (const float*)d_in[23]};
  const float* a_aw[2] = {(const float*)d_in[20], (const float*)d_in[24]};
  const float* a_ab[2] = {(const float*)d_in[21], (const float*)d_in[25]};
  const float* emb2_w = (const float*)d_in[26];
  const float* emb2_b = (const float*)d_in[27];

  float* out    = (float*)d_out;
  float* out_h2 = out;
  float* out_h  = out + 262144;
  float* out_c  = out + 262144 + 786432;
  const int BR = B_ * R_;
  const int ns = 4;

  dim3 blk(256);
  auto jobL = [&](float* C, const ushort* Xb, const float* W1, const float* W2) {
    GJob j;
    j.C = C; j.ldc = 5120; j.pstride = (size_t)256 * 5120;
    j.Xb = Xb; j.ldx = 3072;
    j.W1 = W1; j.ldw1 = 2048; j.K1 = 2048;
    j.W2 = W2; j.ldw2 = 1024;
    j.K = 3072; j.nbn = 80; j.ns = ns;
    return j;
  };
  auto jobS = [&](float* C, int ldc, const ushort* Xb, int ldx,
                  const float* W, int ldw, int K, int N) {
    GJob j;
    j.C = C; j.ldc = ldc; j.pstride = (size_t)256 * ldc;
    j.Xb = Xb; j.ldx = ldx;
    j.W1 = W; j.ldw1 = ldw; j.K1 = K;
    j.W2 = W; j.ldw2 = ldw;
    j.K = K; j.nbn = N / 64; j.ns = ns;
    return j;
  };
  auto launch1 = [&](GJob j) {
    int total = j.nbn * 4 * j.ns;
    hipLaunchKernelGGL(gemm_k, dim3(total), blk, 0, stream, j, j, total);
  };
  auto launch2 = [&](GJob a, GJob b) {
    int ta = a.nbn * 4 * a.ns;
    int tb = b.nbn * 4 * b.ns;
    hipLaunchKernelGGL(gemm_k, dim3(ta + tb), blk, 0, stream, a, b, ta);
  };

  // ---------- workspace ----------
  // new layout needs Sp | Xb0..2 | attHp(4) | sc | q2p(4) | q2b = 32,706,560 B
  const size_t NEED = 32706560u;
  float*  Sp    = (float*)d_ws;                       // 4 x 1310720 f
  ushort* Xb0   = (ushort*)(Sp + (size_t)ns * 1310720);
  ushort* Xb1   = Xb0 + 786432;
  ushort* Xb2   = Xb1 + 786432;
  float*  attHp = (float*)(Xb2 + 786432);             // 4 x 131072 f
  float*  sc    = attHp + (size_t)ns * 131072;        // 50176 f

  if (ws_size >= NEED) {
    // ================= fused path (13 launches) =================
    float*  q2p = sc + 50176;                         // 4 x 262144 f
    ushort* q2b = (ushort*)(q2p + (size_t)4 * 262144);

    pack5<<<1280, 256, 0, stream>>>(xt, Xb0, fc, Xb0 + 1024, st_h, Xb0 + 2048,
                                    st_h + BR, Xb1 + 2048,
                                    st_h + 2 * BR, Xb2 + 2048);

    // ---- LSTM 0
    launch1(jobL(Sp, Xb0, wi[0], wh[0]));
    lstm_gates<<<256, 256, 0, stream>>>(Sp, ns, bi[0], bh[0], st_c,
                                        out_h, out_c, Xb1, nullptr,
                                        nullptr, 0, nullptr, nullptr);

    // ---- Attention 1 (query = h0)
    launch1(jobS(attHp, 512, Xb1, 3072, a_hw[0], 1024, 1024, 512));
    att_scores<<<(B_ * L_) / 4, 256, 0, stream>>>(sc, p_att, attHp, ns,
                                                  a_hb[0], a_aw[0], a_ab[0]);
    att_smw<<<B_ * 4, 256, 0, stream>>>(Xb1 + 1024, sc, att_feats);

    // ---- LSTM1 GEMM || q2 GEMM (both depend only on ar1)
    launch2(jobL(Sp, Xb1, wi[1], wh[1]),
            jobS(q2p, 1024, Xb1 + 1024, 3072, emb2_w, 1024, 1024, 1024));
    // ---- gates1 + fused q2b
    lstm_gates<<<256, 256, 0, stream>>>(Sp, ns, bi[1], bh[1], st_c + BR,
                                        out_h + BR, out_c + BR, Xb2, nullptr,
                                        q2p, 4, emb2_b, q2b);

    // ---- Attention 2 (query = q2b)
    launch1(jobS(attHp, 512, q2b, 1024, a_hw[1], 1024, 1024, 512));
    att_scores<<<(B_ * L_) / 4, 256, 0, stream>>>(sc, p_att, attHp, ns,
                                                  a_hb[1], a_aw[1], a_ab[1]);
    att_smw<<<B_ * 4, 256, 0, stream>>>(Xb2 + 1024, sc, att_feats);

    // ---- LSTM 2
    launch1(jobL(Sp, Xb2, wi[2], wh[2]));
    lstm_gates<<<256, 256, 0, stream>>>(Sp, ns, bi[2], bh[2], st_c + 2 * BR,
                                        out_h + 2 * BR, out_c + 2 * BR,
                                        nullptr, out_h2,
                                        nullptr, 0, nullptr, nullptr);
    return;
  }

  // ================= fallback: exact R8 path (15 launches) =================
  float*  q2p = Sp;                                   // alias (Sp dead)
  ushort* q2b = (ushort*)(Sp + (size_t)ns * 262144);

  pack5<<<1280, 256, 0, stream>>>(xt, Xb0, fc, Xb0 + 1024, st_h, Xb0 + 2048,
                                  st_h + BR, Xb1 + 2048,
                                  st_h + 2 * BR, Xb2 + 2048);
  launch1(jobL(Sp, Xb0, wi[0], wh[0]));
  lstm_gates<<<256, 256, 0, stream>>>(Sp, ns, bi[0], bh[0], st_c,
                                      out_h, out_c, Xb1, nullptr,
                                      nullptr, 0, nullptr, nullptr);
  launch1(jobS(attHp, 512, Xb1, 3072, a_hw[0], 1024, 1024, 512));
  att_scores<<<(B_ * L_) / 4, 256, 0, stream>>>(sc, p_att, attHp, ns,
                                                a_hb[0], a_aw[0], a_ab[0]);
  att_smw<<<B_ * 4, 256, 0, stream>>>(Xb1 + 1024, sc, att_feats);
  launch1(jobL(Sp, Xb1, wi[1], wh[1]));
  lstm_gates<<<256, 256, 0, stream>>>(Sp, ns, bi[1], bh[1], st_c + BR,
                                      out_h + BR, out_c + BR, Xb2, nullptr,
                                      nullptr, 0, nullptr, nullptr);
  launch1(jobS(q2p, 1024, Xb1 + 1024, 3072, emb2_w, 1024, 1024, 1024));
  make_q2<<<256, 256, 0, stream>>>(q2b, q2p, ns, out_h + BR, emb2_b);
  launch1(jobS(attHp, 512, q2b, 1024, a_hw[1], 1024, 1024, 512));
  att_scores<<<(B_ * L_) / 4, 256, 0, stream>>>(sc, p_att, attHp, ns,
                                                a_hb[1], a_aw[1], a_ab[1]);
  att_smw<<<B_ * 4, 256, 0, stream>>>(Xb2 + 1024, sc, att_feats);
  launch1(jobL(Sp, Xb2, wi[2], wh[2]));
  lstm_gates<<<256, 256, 0, stream>>>(Sp, ns, bi[2], bh[2], st_c + 2 * BR,
                                      out_h + 2 * BR, out_c + 2 * BR,
                                      nullptr, out_h2,
                                      nullptr, 0, nullptr, nullptr);
}